// Round 1
// baseline (664.697 us; speedup 1.0000x reference)
//
#include <hip/hip_runtime.h>
#include <stdint.h>

// Problem constants (from reference): B=128, T=64(unused), LATENT=16(unused),
// D=512, N_ENVS=4, TOPK_RATIO=0.1, TEMPERATURE=1.0
#define D_DIM   512
#define DD      262144          // D*D
#define B_DIM   128
#define N_ENVS  4
#define K_SEL   26214           // max(1, int(0.1*512*512))
#define BDD     33554432u       // B*D*D
#define CAP     16384           // max (key,idx) pairs kept per env (expected ~700)

// ---- scratch layout (bytes, within `scratch`) ----
#define HIST_BYTES  (N_ENVS * 65536 * 4)     // 1 MiB  : uint hist[4][65536]
#define CNT_OFF     HIST_BYTES               // 16 B   : uint cnt[4]
#define PK_OFF      (HIST_BYTES + 64)        // 32 B   : uint {prefix16,krem}[4]
#define PAIRS_OFF   (HIST_BYTES + 128)       // 512 KiB: uint2 pairs[4][CAP]
#define PAIRS_BYTES (N_ENVS * CAP * 8)
#define SCRATCH_NEED ((size_t)(PAIRS_OFF + PAIRS_BYTES))

// Order-preserving float->uint key: larger float <=> larger key.
__device__ __forceinline__ uint32_t fkey(float f) {
    uint32_t u = __float_as_uint(f);
    return (u & 0x80000000u) ? ~u : (u | 0x80000000u);
}

__device__ __forceinline__ float sigmoidf_(float x) {
    return 1.0f / (1.0f + __expf(-x));
}

// Pass A: 16-bit MSB histogram of keys, per env. grid (128, N_ENVS) x 256.
__global__ __launch_bounds__(256) void hist16_kernel(
    const float* __restrict__ base, const float* __restrict__ deltas,
    uint32_t* __restrict__ hist)
{
    int e = blockIdx.y;
    const float* dp = deltas + (size_t)e * DD;
    uint32_t* h = hist + (size_t)e * 65536;
    int stride = gridDim.x * blockDim.x;
    for (int i = blockIdx.x * blockDim.x + threadIdx.x; i < DD; i += stride) {
        float v = base[i] + dp[i];
        atomicAdd(&h[fkey(v) >> 16], 1u);
    }
}

// Pass B: scan bins top-down; find the 16-bit prefix bin containing the k-th
// largest element and the residual rank krem (1-based) within that bin.
// grid N_ENVS x 256.
__global__ __launch_bounds__(256) void findbin_kernel(
    const uint32_t* __restrict__ hist, uint32_t* __restrict__ pk)
{
    int e = blockIdx.x;
    const uint32_t* h = hist + (size_t)e * 65536;
    __shared__ uint32_t s_val[256];
    __shared__ uint32_t s_red[256];
    __shared__ uint32_t s_cum;
    __shared__ int s_done;
    int tid = threadIdx.x;
    if (tid == 0) { s_cum = 0; s_done = 0; }
    __syncthreads();
    for (int c = 0; c < 256; ++c) {
        int bin = 65535 - (c * 256 + tid);      // tid 0 = highest bin in chunk
        uint32_t v = h[bin];
        s_val[tid] = v; s_red[tid] = v;
        __syncthreads();
        for (int off = 128; off > 0; off >>= 1) {
            if (tid < off) s_red[tid] += s_red[tid + off];
            __syncthreads();
        }
        if (tid == 0) {
            uint32_t tot = s_red[0];
            if (s_cum + tot >= (uint32_t)K_SEL) {
                uint32_t cum = s_cum;
                for (int j = 0; j < 256; ++j) {
                    uint32_t nc = cum + s_val[j];
                    if (nc >= (uint32_t)K_SEL) {
                        pk[2 * e + 0] = (uint32_t)(65535 - (c * 256 + j)); // prefix16
                        pk[2 * e + 1] = (uint32_t)K_SEL - cum;             // krem >= 1
                        break;
                    }
                    cum = nc;
                }
                s_done = 1;
            } else {
                s_cum += tot;
            }
        }
        __syncthreads();
        if (s_done) break;
    }
}

// Pass C: gather (key, idx) of all elements whose top-16 bits == prefix16.
// grid (128, N_ENVS) x 256.
__global__ __launch_bounds__(256) void gather_kernel(
    const float* __restrict__ base, const float* __restrict__ deltas,
    const uint32_t* __restrict__ pk, uint32_t* __restrict__ cnt,
    uint2* __restrict__ pairs)
{
    int e = blockIdx.y;
    uint32_t pref = pk[2 * e];
    const float* dp = deltas + (size_t)e * DD;
    uint2* p = pairs + (size_t)e * CAP;
    int stride = gridDim.x * blockDim.x;
    for (int i = blockIdx.x * blockDim.x + threadIdx.x; i < DD; i += stride) {
        float v = base[i] + dp[i];
        uint32_t key = fkey(v);
        if ((key >> 16) == pref) {
            uint32_t pos = atomicAdd(&cnt[e], 1u);
            if (pos < CAP) p[pos] = make_uint2(key, (uint32_t)i);
        }
    }
}

// Pass D: exact rank selection among the in-bin pairs. The element of rank
// krem-1 (key desc, idx asc — jax.lax.top_k tie rule) gives (T, cutoff_idx).
// grid N_ENVS x 256.
__global__ __launch_bounds__(256) void select_kernel(
    const uint32_t* __restrict__ pk, const uint32_t* __restrict__ cnt,
    const uint2* __restrict__ pairs, uint32_t* __restrict__ thrcut)
{
    int e = blockIdx.x;
    uint32_t M = cnt[e]; if (M > CAP) M = CAP;
    uint32_t target = pk[2 * e + 1] - 1;   // 0-based rank of threshold element
    const uint2* p = pairs + (size_t)e * CAP;
    for (uint32_t j = threadIdx.x; j < M; j += blockDim.x) {
        uint2 me = p[j];
        uint32_t rank = 0;
        for (uint32_t l = 0; l < M; ++l) {
            uint2 o = p[l];
            rank += (o.x > me.x) || (o.x == me.x && o.y < me.y);
        }
        if (rank == target) {
            thrcut[2 * e + 0] = me.x;   // threshold key T
            thrcut[2 * e + 1] = me.y;   // cutoff flat index
        }
    }
}

// Pass E: produce all three outputs. Selection: key > T, or key == T and
// flat index <= cutoff (lower-index-first tie rule).
// grid (DD/4/256, B) x 256; each thread handles one float4 group.
__global__ __launch_bounds__(256) void write_kernel(
    const int* __restrict__ env_idx, const float* __restrict__ base,
    const float* __restrict__ deltas, const uint32_t* __restrict__ thrcut,
    float* __restrict__ out)
{
    int b = blockIdx.y;
    int e = env_idx[b];
    uint32_t T = thrcut[2 * e], C = thrcut[2 * e + 1];
    int g = blockIdx.x * blockDim.x + threadIdx.x;   // float4 group in [0, DD/4)
    uint32_t i0 = (uint32_t)g * 4u;

    float4 bv = ((const float4*)base)[g];
    float4 dv = ((const float4*)(deltas + (size_t)e * DD))[g];
    float4 lg = make_float4(bv.x + dv.x, bv.y + dv.y, bv.z + dv.z, bv.w + dv.w);
    float4 sg = make_float4(sigmoidf_(lg.x), sigmoidf_(lg.y),
                            sigmoidf_(lg.z), sigmoidf_(lg.w));
    uint32_t kx = fkey(lg.x), ky = fkey(lg.y), kz = fkey(lg.z), kw = fkey(lg.w);
    float4 av;
    av.x = (kx > T || (kx == T && i0 + 0u <= C)) ? sg.x : 0.0f;
    av.y = (ky > T || (ky == T && i0 + 1u <= C)) ? sg.y : 0.0f;
    av.z = (kz > T || (kz == T && i0 + 2u <= C)) ? sg.z : 0.0f;
    av.w = (kw > T || (kw == T && i0 + 3u <= C)) ? sg.w : 0.0f;

    size_t o = (size_t)b * (DD / 4) + (size_t)g;
    ((float4*)out)[o]                    = av;   // A
    ((float4*)out)[o + (BDD / 4)]        = lg;   // A_logits
    ((float4*)out)[o + 2ull * (BDD / 4)] = sg;   // A_soft
}

extern "C" void kernel_launch(void* const* d_in, const int* in_sizes, int n_in,
                              void* d_out, int out_size, void* d_ws, size_t ws_size,
                              hipStream_t stream) {
    // inputs: 0=z_s (unused), 1=env_idx (int32), 2=A_base (f32), 3=A_deltas (f32)
    const int*   env_idx  = (const int*)d_in[1];
    const float* A_base   = (const float*)d_in[2];
    const float* A_deltas = (const float*)d_in[3];
    float* out = (float*)d_out;

    // thr/cut (32 B) always lives in d_ws so it survives write_kernel.
    uint32_t* thrcut = (uint32_t*)d_ws;

    // Bulk scratch (hist + pairs, ~1.5 MiB): prefer d_ws; if the workspace is
    // too small, carve the tail of d_out — write_kernel rewrites every output
    // element afterwards, and nothing reads the carve after select_kernel.
    size_t out_bytes = (size_t)out_size * sizeof(float);
    char* scratch;
    if (ws_size >= 256 + SCRATCH_NEED) {
        scratch = (char*)d_ws + 256;
    } else {
        scratch = (char*)d_out + ((out_bytes - SCRATCH_NEED) & ~(size_t)255);
    }

    uint32_t* hist  = (uint32_t*)(scratch);
    uint32_t* cnt   = (uint32_t*)(scratch + CNT_OFF);
    uint32_t* pk    = (uint32_t*)(scratch + PK_OFF);
    uint2*    pairs = (uint2*)   (scratch + PAIRS_OFF);

    // Zero hist + cnt (d_ws/d_out are poisoned 0xAA before every call).
    hipMemsetAsync(scratch, 0, HIST_BYTES + 64, stream);

    hist16_kernel <<<dim3(128, N_ENVS), 256, 0, stream>>>(A_base, A_deltas, hist);
    findbin_kernel<<<N_ENVS,            256, 0, stream>>>(hist, pk);
    gather_kernel <<<dim3(128, N_ENVS), 256, 0, stream>>>(A_base, A_deltas, pk, cnt, pairs);
    select_kernel <<<N_ENVS,            256, 0, stream>>>(pk, cnt, pairs, thrcut);
    write_kernel  <<<dim3(DD / 4 / 256, B_DIM), 256, 0, stream>>>(
        env_idx, A_base, A_deltas, thrcut, out);
}

// Round 4
// 466.064 us; speedup vs baseline: 1.4262x; 1.4262x over previous
//
#include <hip/hip_runtime.h>
#include <stdint.h>

// Problem constants: B=128, D=512, N_ENVS=4, k = int(0.1*512*512) = 26214.
#define D_DIM   512
#define DD      262144                    // D*D
#define DD4     65536                     // DD / 4 (float4 groups)
#define B_DIM   128
#define N_ENVS  4
#define K_SEL   26214
#define BDD     33554432u                 // B*D*D
#define CAP2    65536                     // max gathered pairs per env (byte-bin; expect ~28K)
#define CAP3    4096                      // max in-LDS pairs for final rank select (expect ~450)

// Native 16-byte vector type (legal operand for __builtin_nontemporal_store).
typedef float nfloat4 __attribute__((ext_vector_type(4)));

// ---- workspace layout (bytes) ----
// [0,32)        thrcut[4][2]  {threshold key, cutoff idx}
// [64,96)       pk[4][2]      {prefix8, krem8}
// [128,144)     cnt8[4]
// [192,4288)    hist8[4][256]  (4 KiB — NOT 1 KiB; round-3 bug was zeroing only 1 KiB)
// [8192, +2MB)  pairs8[4][CAP2] (uint2)
// [PLANES_OFF, +12MB) planes[4][3][DD] floats: {A, logits, soft} per env
#define PK_OFF      64
#define CNT_OFF     128
#define HIST_OFF    192
#define HIST_BYTES  (N_ENVS * 256 * 4)                   // 4096
#define ZERO_BYTES  (HIST_OFF + HIST_BYTES - PK_OFF)     // pk..hist8 inclusive
#define PAIRS_OFF   8192
#define PAIRS_BYTES ((size_t)N_ENVS * CAP2 * 8)          // 2 MiB
#define PLANES_OFF  (PAIRS_OFF + PAIRS_BYTES)
#define PLANES_BYTES ((size_t)N_ENVS * 3 * DD * 4)       // 12 MiB
#define WS_NEED     (PLANES_OFF + PLANES_BYTES)
#define SEL_NEED    (PAIRS_OFF + PAIRS_BYTES)            // selection-only scratch

// Order-preserving float->uint key: larger float <=> larger key.
__device__ __forceinline__ uint32_t fkey(float f) {
    uint32_t u = __float_as_uint(f);
    return (u & 0x80000000u) ? ~u : (u | 0x80000000u);
}
__device__ __forceinline__ float sigmoidf_(float x) {
    return 1.0f / (1.0f + __expf(-x));
}

// ---- M1: top-8-bit histogram of keys, per env. grid (64, 4) x 256. ----
__global__ __launch_bounds__(256) void hist8_kernel(
    const float* __restrict__ base, const float* __restrict__ deltas,
    uint32_t* __restrict__ hist8)
{
    int e = blockIdx.y;
    const float4* b4 = (const float4*)base;
    const float4* d4 = (const float4*)(deltas + (size_t)e * DD);
    __shared__ uint32_t s_h[256];
    int tid = threadIdx.x;
    s_h[tid] = 0;
    __syncthreads();
    int g0 = blockIdx.x * 256 + tid;                 // float4 group
    #pragma unroll
    for (int r = 0; r < 4; ++r) {
        int g = g0 + r * 16384;                      // 64 blocks * 256 threads
        float4 bv = b4[g], dv = d4[g];
        atomicAdd(&s_h[fkey(bv.x + dv.x) >> 24], 1u);
        atomicAdd(&s_h[fkey(bv.y + dv.y) >> 24], 1u);
        atomicAdd(&s_h[fkey(bv.z + dv.z) >> 24], 1u);
        atomicAdd(&s_h[fkey(bv.w + dv.w) >> 24], 1u);
    }
    __syncthreads();
    if (s_h[tid]) atomicAdd(&hist8[e * 256 + tid], s_h[tid]);
}

// ---- M2: find byte-bin P + krem8; gather (key,idx) with key>>24==P. ----
// grid (64, 4) x 256. Block-aggregated global counter (1 atomic per block).
__global__ __launch_bounds__(256) void gather8_kernel(
    const float* __restrict__ base, const float* __restrict__ deltas,
    const uint32_t* __restrict__ hist8, uint32_t* __restrict__ pk,
    uint32_t* __restrict__ cnt8, uint2* __restrict__ pairs8)
{
    int e = blockIdx.y;
    const float4* b4 = (const float4*)base;
    const float4* d4 = (const float4*)(deltas + (size_t)e * DD);
    uint2* pp = pairs8 + (size_t)e * CAP2;
    __shared__ uint32_t s_h[256];
    __shared__ uint32_t s_scan[256];
    __shared__ uint32_t s_P, s_base;
    int tid = threadIdx.x;

    s_h[tid] = hist8[e * 256 + tid];
    __syncthreads();
    if (tid == 0) {
        uint32_t cum = 0;
        for (int b = 255; b >= 0; --b) {
            uint32_t c = s_h[b];
            if (cum + c >= (uint32_t)K_SEL) {
                s_P = (uint32_t)b;
                if (blockIdx.x == 0) {
                    pk[2 * e + 0] = (uint32_t)b;
                    pk[2 * e + 1] = (uint32_t)K_SEL - cum;   // krem8 >= 1
                }
                break;
            }
            cum += c;
        }
    }
    __syncthreads();
    uint32_t P = s_P;

    // Phase 1: count my matches.
    int g0 = blockIdx.x * 256 + tid;
    uint32_t m = 0;
    #pragma unroll
    for (int r = 0; r < 4; ++r) {
        int g = g0 + r * 16384;
        float4 bv = b4[g], dv = d4[g];
        m += ((fkey(bv.x + dv.x) >> 24) == P);
        m += ((fkey(bv.y + dv.y) >> 24) == P);
        m += ((fkey(bv.z + dv.z) >> 24) == P);
        m += ((fkey(bv.w + dv.w) >> 24) == P);
    }
    // Inclusive Hillis-Steele scan over 256 threads.
    s_scan[tid] = m;
    __syncthreads();
    #pragma unroll
    for (int off = 1; off < 256; off <<= 1) {
        uint32_t v = (tid >= off) ? s_scan[tid - off] : 0u;
        __syncthreads();
        s_scan[tid] += v;
        __syncthreads();
    }
    uint32_t excl = s_scan[tid] - m;
    if (tid == 255) s_base = atomicAdd(&cnt8[e], s_scan[255]);
    __syncthreads();
    uint32_t pos = s_base + excl;

    // Phase 2: re-read and scatter.
    #pragma unroll
    for (int r = 0; r < 4; ++r) {
        int g = g0 + r * 16384;
        float4 bv = b4[g], dv = d4[g];
        float vs[4] = {bv.x + dv.x, bv.y + dv.y, bv.z + dv.z, bv.w + dv.w};
        #pragma unroll
        for (int j = 0; j < 4; ++j) {
            uint32_t key = fkey(vs[j]);
            if ((key >> 24) == P) {
                if (pos < CAP2) pp[pos] = make_uint2(key, (uint32_t)(g * 4 + j));
                ++pos;
            }
        }
    }
}

// ---- M3: refine within byte-bin (bits 16-23), gather sub-bin to LDS, ----
// ---- exact rank select (key desc, idx asc). grid 4 x 1024. ----
__global__ __launch_bounds__(1024) void select2_kernel(
    const uint32_t* __restrict__ pk, const uint32_t* __restrict__ cnt8,
    const uint2* __restrict__ pairs8, uint32_t* __restrict__ thrcut)
{
    int e = blockIdx.x;
    const uint2* pp = pairs8 + (size_t)e * CAP2;
    uint32_t M = cnt8[e]; if (M > CAP2) M = CAP2;
    uint32_t krem8 = pk[2 * e + 1];

    __shared__ uint32_t s_h16[256];
    __shared__ uint2    s_pairs[CAP3];
    __shared__ uint32_t s_b16, s_krem16, s_cnt;
    int tid = threadIdx.x;
    if (tid < 256) s_h16[tid] = 0;
    if (tid == 0) s_cnt = 0;
    __syncthreads();

    for (uint32_t j = tid; j < M; j += 1024)
        atomicAdd(&s_h16[(pp[j].x >> 16) & 255u], 1u);
    __syncthreads();
    if (tid == 0) {
        uint32_t cum = 0;
        for (int b = 255; b >= 0; --b) {
            uint32_t c = s_h16[b];
            if (cum + c >= krem8) { s_b16 = (uint32_t)b; s_krem16 = krem8 - cum; break; }
            cum += c;
        }
    }
    __syncthreads();
    uint32_t b16 = s_b16;
    for (uint32_t j = tid; j < M; j += 1024) {
        uint2 p = pp[j];
        if (((p.x >> 16) & 255u) == b16) {
            uint32_t pos = atomicAdd(&s_cnt, 1u);
            if (pos < CAP3) s_pairs[pos] = p;
        }
    }
    __syncthreads();
    uint32_t M2 = s_cnt; if (M2 > CAP3) M2 = CAP3;
    uint32_t target = s_krem16 - 1;                  // 0-based rank
    for (uint32_t j = tid; j < M2; j += 1024) {
        uint2 me = s_pairs[j];
        uint32_t rank = 0;
        for (uint32_t l = 0; l < M2; ++l) {
            uint2 o = s_pairs[l];
            rank += (o.x > me.x) || (o.x == me.x && o.y < me.y);
        }
        if (rank == target) {
            thrcut[2 * e + 0] = me.x;
            thrcut[2 * e + 1] = me.y;
        }
    }
}

// ---- M4: compute the 4 distinct (A, logits, soft) planes into ws. ----
// grid (256, 4) x 256.
__global__ __launch_bounds__(256) void planes_kernel(
    const float* __restrict__ base, const float* __restrict__ deltas,
    const uint32_t* __restrict__ thrcut, float* __restrict__ planes)
{
    int e = blockIdx.y;
    int g = blockIdx.x * 256 + threadIdx.x;          // float4 group in [0, DD4)
    uint32_t T = thrcut[2 * e], C = thrcut[2 * e + 1];
    uint32_t i0 = (uint32_t)g * 4u;
    float4 bv = ((const float4*)base)[g];
    float4 dv = ((const float4*)(deltas + (size_t)e * DD))[g];
    nfloat4 lg = { bv.x + dv.x, bv.y + dv.y, bv.z + dv.z, bv.w + dv.w };
    nfloat4 sg = { sigmoidf_(lg.x), sigmoidf_(lg.y),
                   sigmoidf_(lg.z), sigmoidf_(lg.w) };
    uint32_t kx = fkey(lg.x), ky = fkey(lg.y), kz = fkey(lg.z), kw = fkey(lg.w);
    nfloat4 av;
    av.x = (kx > T || (kx == T && i0 + 0u <= C)) ? sg.x : 0.0f;
    av.y = (ky > T || (ky == T && i0 + 1u <= C)) ? sg.y : 0.0f;
    av.z = (kz > T || (kz == T && i0 + 2u <= C)) ? sg.z : 0.0f;
    av.w = (kw > T || (kw == T && i0 + 3u <= C)) ? sg.w : 0.0f;
    nfloat4* pl = (nfloat4*)(planes + (size_t)e * 3 * DD);
    pl[g]           = av;
    pl[g + DD4]     = lg;
    pl[g + 2 * DD4] = sg;
}

// ---- M5: broadcast planes to the 128 output rows (pure copy, nt stores). ----
// grid (256, 128) x 256.
__global__ __launch_bounds__(256) void broadcast_kernel(
    const int* __restrict__ env_idx, const float* __restrict__ planes,
    float* __restrict__ out)
{
    int b = blockIdx.y;
    int e = env_idx[b];
    int g = blockIdx.x * 256 + threadIdx.x;
    const nfloat4* pl = (const nfloat4*)(planes + (size_t)e * 3 * DD);
    nfloat4 av = pl[g], lg = pl[g + DD4], sg = pl[g + 2 * DD4];
    nfloat4* o = (nfloat4*)out + (size_t)b * DD4 + g;
    __builtin_nontemporal_store(av, o);
    __builtin_nontemporal_store(lg, o + (BDD / 4));
    __builtin_nontemporal_store(sg, o + 2ull * (BDD / 4));
}

// ---- Fallback fused write (used only if ws too small for planes). ----
__global__ __launch_bounds__(256) void fused_write_kernel(
    const int* __restrict__ env_idx, const float* __restrict__ base,
    const float* __restrict__ deltas, const uint32_t* __restrict__ thrcut,
    float* __restrict__ out)
{
    int b = blockIdx.y;
    int e = env_idx[b];
    uint32_t T = thrcut[2 * e], C = thrcut[2 * e + 1];
    int g = blockIdx.x * 256 + threadIdx.x;
    uint32_t i0 = (uint32_t)g * 4u;
    float4 bv = ((const float4*)base)[g];
    float4 dv = ((const float4*)(deltas + (size_t)e * DD))[g];
    nfloat4 lg = { bv.x + dv.x, bv.y + dv.y, bv.z + dv.z, bv.w + dv.w };
    nfloat4 sg = { sigmoidf_(lg.x), sigmoidf_(lg.y),
                   sigmoidf_(lg.z), sigmoidf_(lg.w) };
    uint32_t kx = fkey(lg.x), ky = fkey(lg.y), kz = fkey(lg.z), kw = fkey(lg.w);
    nfloat4 av;
    av.x = (kx > T || (kx == T && i0 + 0u <= C)) ? sg.x : 0.0f;
    av.y = (ky > T || (ky == T && i0 + 1u <= C)) ? sg.y : 0.0f;
    av.z = (kz > T || (kz == T && i0 + 2u <= C)) ? sg.z : 0.0f;
    av.w = (kw > T || (kw == T && i0 + 3u <= C)) ? sg.w : 0.0f;
    size_t o = (size_t)b * DD4 + (size_t)g;
    nfloat4* o4 = (nfloat4*)out;
    __builtin_nontemporal_store(av, o4 + o);
    __builtin_nontemporal_store(lg, o4 + o + (BDD / 4));
    __builtin_nontemporal_store(sg, o4 + o + 2ull * (BDD / 4));
}

extern "C" void kernel_launch(void* const* d_in, const int* in_sizes, int n_in,
                              void* d_out, int out_size, void* d_ws, size_t ws_size,
                              hipStream_t stream) {
    // inputs: 0=z_s (unused), 1=env_idx (int32), 2=A_base (f32), 3=A_deltas (f32)
    const int*   env_idx  = (const int*)d_in[1];
    const float* A_base   = (const float*)d_in[2];
    const float* A_deltas = (const float*)d_in[3];
    float* out = (float*)d_out;

    uint32_t* thrcut = (uint32_t*)d_ws;   // 32 B, must survive to the write

    bool plane_path = (ws_size >= WS_NEED);
    char* scratch;
    if (ws_size >= SEL_NEED) {
        scratch = (char*)d_ws;
    } else {
        // Carve selection scratch from d_out's tail; it is dead before the
        // fused write rewrites every output element.
        size_t out_bytes = (size_t)out_size * sizeof(float);
        scratch = (char*)d_out + ((out_bytes - SEL_NEED) & ~(size_t)255);
        plane_path = false;
    }
    uint32_t* pk     = (uint32_t*)(scratch + PK_OFF);
    uint32_t* cnt8   = (uint32_t*)(scratch + CNT_OFF);
    uint32_t* hist8  = (uint32_t*)(scratch + HIST_OFF);
    uint2*    pairs8 = (uint2*)   (scratch + PAIRS_OFF);
    float*    planes = (float*)((char*)d_ws + PLANES_OFF);

    // Zero pk + cnt8 + the FULL 4 KiB hist8 (round-3 bug: only 1 KiB zeroed,
    // envs 1-3 accumulated onto 0xAA poison -> garbage threshold).
    (void)hipMemsetAsync(scratch + PK_OFF, 0, ZERO_BYTES, stream);

    hist8_kernel  <<<dim3(64, N_ENVS), 256, 0, stream>>>(A_base, A_deltas, hist8);
    gather8_kernel<<<dim3(64, N_ENVS), 256, 0, stream>>>(A_base, A_deltas, hist8,
                                                         pk, cnt8, pairs8);
    select2_kernel<<<N_ENVS, 1024, 0, stream>>>(pk, cnt8, pairs8, thrcut);
    if (plane_path) {
        planes_kernel   <<<dim3(DD4 / 256, N_ENVS), 256, 0, stream>>>(
            A_base, A_deltas, thrcut, planes);
        broadcast_kernel<<<dim3(DD4 / 256, B_DIM),  256, 0, stream>>>(
            env_idx, planes, out);
    } else {
        fused_write_kernel<<<dim3(DD4 / 256, B_DIM), 256, 0, stream>>>(
            env_idx, A_base, A_deltas, thrcut, out);
    }
}